// Round 3
// baseline (316.741 us; speedup 1.0000x reference)
//
#include <hip/hip_runtime.h>
#include <hip/hip_bf16.h>
#include <cstdint>
#include <cstddef>

#define B_ROWS 16384
#define D_DIM  256
#define TEMP_INV 14.285714285714286f   // 1/0.07

#define BM 128
#define BN 128
#define BK 128

using frag_ab = __attribute__((ext_vector_type(8))) short;   // 8 bf16
using frag_cd = __attribute__((ext_vector_type(4))) float;   // 4 fp32

__device__ __forceinline__ void gld_lds16(const void* g, void* l) {
    __builtin_amdgcn_global_load_lds(
        (const __attribute__((address_space(1))) void*)g,
        (__attribute__((address_space(3))) void*)l,
        16, 0, 0);
}

// Kernel 1: L2-normalize q,d rows -> bf16; diag[i] = cos(q_i,d_i)/T in fp32.
// Also zero-initializes row_sums/col_sums/out (replaces memset dispatches).
__global__ __launch_bounds__(256) void norm_diag_kernel(
    const float* __restrict__ q, const float* __restrict__ d,
    __hip_bfloat16* __restrict__ qn, __hip_bfloat16* __restrict__ dn,
    float* __restrict__ diag,
    float* __restrict__ row_sums, float* __restrict__ col_sums,
    float* __restrict__ out) {
    const int b = blockIdx.x;
    if (b < 64)            row_sums[b * 256 + threadIdx.x] = 0.0f;
    else if (b < 128)      col_sums[(b - 64) * 256 + threadIdx.x] = 0.0f;
    else if (b == 128 && threadIdx.x == 0) out[0] = 0.0f;

    const int row  = b * 4 + (threadIdx.x >> 6);
    const int lane = threadIdx.x & 63;

    const float4 qv = ((const float4*)(q + (size_t)row * D_DIM))[lane];
    const float4 dv = ((const float4*)(d + (size_t)row * D_DIM))[lane];

    float qss = qv.x*qv.x + qv.y*qv.y + qv.z*qv.z + qv.w*qv.w;
    float dss = dv.x*dv.x + dv.y*dv.y + dv.z*dv.z + dv.w*dv.w;
    float qd  = qv.x*dv.x + qv.y*dv.y + qv.z*dv.z + qv.w*dv.w;
#pragma unroll
    for (int off = 32; off; off >>= 1) {
        qss += __shfl_down(qss, off);
        dss += __shfl_down(dss, off);
        qd  += __shfl_down(qd,  off);
    }
    qss = __shfl(qss, 0);
    dss = __shfl(dss, 0);
    qd  = __shfl(qd,  0);

    const float qinv = 1.0f / fmaxf(sqrtf(qss), 1e-12f);
    const float dinv = 1.0f / fmaxf(sqrtf(dss), 1e-12f);

    struct alignas(8) bf4 { __hip_bfloat16 x, y, z, w; };
    bf4 qo, doo;
    qo.x = __float2bfloat16(qv.x * qinv);
    qo.y = __float2bfloat16(qv.y * qinv);
    qo.z = __float2bfloat16(qv.z * qinv);
    qo.w = __float2bfloat16(qv.w * qinv);
    doo.x = __float2bfloat16(dv.x * dinv);
    doo.y = __float2bfloat16(dv.y * dinv);
    doo.z = __float2bfloat16(dv.z * dinv);
    doo.w = __float2bfloat16(dv.w * dinv);
    *(bf4*)(qn + (size_t)row * D_DIM + lane * 4) = qo;
    *(bf4*)(dn + (size_t)row * D_DIM + lane * 4) = doo;

    if (lane == 0) diag[row] = qd * qinv * dinv * TEMP_INV;
}

// Kernel 2: 128x128 tile of sim = qn . dn^T; fused exp(sim - 1/T) row/col partial sums.
// BK=128: K=256 in 2 stages -> 3 barriers/block (was 7), 16 gld_lds in flight/stage.
// LDS XOR swizzle: row r is 16 chunks of 16B; physical chunk p holds logical chunk
// (p&8)|((p&7)^(r&7)). Staging keeps the wave-uniform-base + lane*16 contiguity
// global_load_lds requires; readers apply the same XOR. 2 lanes/bank -> conflict-free.
__global__ __launch_bounds__(256) void gemm_lse_kernel(
    const __hip_bfloat16* __restrict__ qn, const __hip_bfloat16* __restrict__ dn,
    float* __restrict__ row_sums, float* __restrict__ col_sums) {
    __shared__ __hip_bfloat16 As[BM][BK];   // 32 KB
    __shared__ __hip_bfloat16 Bs[BN][BK];   // 32 KB
    __shared__ float rowbuf[BM];
    __shared__ float colbuf[BN];

    const int t    = threadIdx.x;
    const int lane = t & 63;
    const int w    = t >> 6;
    const int l15  = lane & 15;
    const int quad = lane >> 4;
    const int m0   = (w >> 1) * 64;
    const int n0   = (w & 1) * 64;
    const int rowBase = blockIdx.y * BM;
    const int colBase = blockIdx.x * BN;

    if (t < BM) rowbuf[t] = 0.0f;
    else        colbuf[t - BM] = 0.0f;

    // staging: issue i in [0,8): chunk index c = i*256 + t; row r = c>>4 = i*16 + (t>>4);
    // physical chunk p = t&15; global logical chunk g = (p&8)|((p&7)^(r&7)).
    // (i*16 rows keeps r&7 invariant across issues.)
    const int r0 = t >> 4;
    const int p  = t & 15;
    const int g  = (p & 8) | ((p & 7) ^ (r0 & 7));
    const __hip_bfloat16* ga = qn + (size_t)(rowBase + r0) * D_DIM + g * 8;
    const __hip_bfloat16* gb = dn + (size_t)(colBase + r0) * D_DIM + g * 8;
    __hip_bfloat16* la = &As[0][0] + t * 8;   // + i*2048 elems per issue
    __hip_bfloat16* lb = &Bs[0][0] + t * 8;

    frag_cd acc[4][4];
#pragma unroll
    for (int i = 0; i < 4; ++i)
#pragma unroll
        for (int j = 0; j < 4; ++j)
            acc[i][j] = (frag_cd){0.0f, 0.0f, 0.0f, 0.0f};

    for (int kt = 0; kt < D_DIM; kt += BK) {
        if (kt) __syncthreads();
#pragma unroll
        for (int it = 0; it < 8; ++it) {   // 16 loads in flight per thread
            gld_lds16(ga + (size_t)it * 16 * D_DIM + kt, la + it * 2048);
            gld_lds16(gb + (size_t)it * 16 * D_DIM + kt, lb + it * 2048);
        }
        __syncthreads();   // drains vmcnt (global_load_lds) + orders LDS

#pragma unroll
        for (int ks = 0; ks < 4; ++ks) {
            const int c = ks * 4 + quad;             // logical 16B-chunk index
            frag_ab af[4], bfr[4];
#pragma unroll
            for (int i = 0; i < 4; ++i) {
                const int R  = m0 + i * 16 + l15;
                const int pc = (c & 8) | ((c & 7) ^ (l15 & 7));
                af[i] = *(const frag_ab*)&As[R][pc * 8];
            }
#pragma unroll
            for (int i = 0; i < 4; ++i) {
                const int R  = n0 + i * 16 + l15;
                const int pc = (c & 8) | ((c & 7) ^ (l15 & 7));
                bfr[i] = *(const frag_ab*)&Bs[R][pc * 8];
            }
#pragma unroll
            for (int mi = 0; mi < 4; ++mi)
#pragma unroll
                for (int ni = 0; ni < 4; ++ni)
                    acc[mi][ni] = __builtin_amdgcn_mfma_f32_16x16x32_bf16(
                        af[mi], bfr[ni], acc[mi][ni], 0, 0, 0);
        }
    }

    // Epilogue: e = exp((cos - 1)/T); reduce to per-row / per-col partial sums.
    // C frag layout: col = lane&15, row = quad*4 + r (m89-verified).
    float csum[4] = {0.0f, 0.0f, 0.0f, 0.0f};
#pragma unroll
    for (int mi = 0; mi < 4; ++mi) {
        float rs[4] = {0.0f, 0.0f, 0.0f, 0.0f};
#pragma unroll
        for (int ni = 0; ni < 4; ++ni) {
#pragma unroll
            for (int r = 0; r < 4; ++r) {
                const float e = __expf((acc[mi][ni][r] - 1.0f) * TEMP_INV);
                rs[r]    += e;
                csum[ni] += e;
            }
        }
#pragma unroll
        for (int off = 8; off; off >>= 1)
#pragma unroll
            for (int r = 0; r < 4; ++r) rs[r] += __shfl_xor(rs[r], off);
        if (l15 == 0)
#pragma unroll
            for (int r = 0; r < 4; ++r)
                atomicAdd(&rowbuf[m0 + mi * 16 + quad * 4 + r], rs[r]);
    }
#pragma unroll
    for (int off = 16; off <= 32; off <<= 1)
#pragma unroll
        for (int ni = 0; ni < 4; ++ni) csum[ni] += __shfl_xor(csum[ni], off);
    if (quad == 0)
#pragma unroll
        for (int ni = 0; ni < 4; ++ni)
            atomicAdd(&colbuf[n0 + ni * 16 + l15], csum[ni]);

    __syncthreads();
    if (t < BM) atomicAdd(&row_sums[rowBase + t], rowbuf[t]);
    else        atomicAdd(&col_sums[colBase + (t - BM)], colbuf[t - BM]);
}

// Kernel 3 (parallel): each block reduces 256 rows, atomicAdd into zeroed out[0].
__global__ __launch_bounds__(256) void finalize_kernel(
    const float* __restrict__ rs, const float* __restrict__ cs,
    const float* __restrict__ dg, float* __restrict__ out) {
    const int i = blockIdx.x * 256 + threadIdx.x;
    float s = logf(rs[i]) + logf(cs[i]) - 2.0f * dg[i];
#pragma unroll
    for (int off = 32; off; off >>= 1) s += __shfl_down(s, off);
    __shared__ float buf[4];
    if ((threadIdx.x & 63) == 0) buf[threadIdx.x >> 6] = s;
    __syncthreads();
    if (threadIdx.x == 0) {
        float tot = (buf[0] + buf[1] + buf[2] + buf[3]) / (2.0f * B_ROWS);
        if (blockIdx.x == 0) tot += TEMP_INV;   // undo the fixed exp shift
        atomicAdd(out, tot);
    }
}

extern "C" void kernel_launch(void* const* d_in, const int* in_sizes, int n_in,
                              void* d_out, int out_size, void* d_ws, size_t ws_size,
                              hipStream_t stream) {
    const float* q = (const float*)d_in[0];
    const float* d = (const float*)d_in[1];
    float* out = (float*)d_out;

    char* ws = (char*)d_ws;
    __hip_bfloat16* qn = (__hip_bfloat16*)ws;                       // 8 MB
    __hip_bfloat16* dn = qn + (size_t)B_ROWS * D_DIM;               // 8 MB
    float* row_sums = (float*)(ws + 2 * (size_t)B_ROWS * D_DIM * sizeof(__hip_bfloat16));
    float* col_sums = row_sums + B_ROWS;
    float* diag     = col_sums + B_ROWS;

    norm_diag_kernel<<<B_ROWS / 4, 256, 0, stream>>>(q, d, qn, dn, diag,
                                                     row_sums, col_sums, out);
    gemm_lse_kernel<<<dim3(B_ROWS / BN, B_ROWS / BM), 256, 0, stream>>>(qn, dn, row_sums, col_sums);
    finalize_kernel<<<B_ROWS / 256, 256, 0, stream>>>(row_sums, col_sums, diag, out);
}

// Round 4
// 260.840 us; speedup vs baseline: 1.2143x; 1.2143x over previous
//
#include <hip/hip_runtime.h>
#include <hip/hip_bf16.h>
#include <cstdint>
#include <cstddef>

#define B_ROWS 16384
#define D_DIM  256
#define TEMP_INV 14.285714285714286f   // 1/0.07

#define BM 128
#define BN 128
#define BK 64

using frag_ab = __attribute__((ext_vector_type(8))) short;   // 8 bf16
using frag_cd = __attribute__((ext_vector_type(4))) float;   // 4 fp32

__device__ __forceinline__ void gld_lds16(const void* g, void* l) {
    __builtin_amdgcn_global_load_lds(
        (const __attribute__((address_space(1))) void*)g,
        (__attribute__((address_space(3))) void*)l,
        16, 0, 0);
}

// Kernel 1: L2-normalize q,d rows -> bf16; diag[i] = cos(q_i,d_i)/T in fp32.
// Also zero-initializes row_sums/col_sums/out (replaces memset dispatches).
__global__ __launch_bounds__(256) void norm_diag_kernel(
    const float* __restrict__ q, const float* __restrict__ d,
    __hip_bfloat16* __restrict__ qn, __hip_bfloat16* __restrict__ dn,
    float* __restrict__ diag,
    float* __restrict__ row_sums, float* __restrict__ col_sums,
    float* __restrict__ out) {
    const int b = blockIdx.x;
    if (b < 64)            row_sums[b * 256 + threadIdx.x] = 0.0f;
    else if (b < 128)      col_sums[(b - 64) * 256 + threadIdx.x] = 0.0f;
    else if (b == 128 && threadIdx.x == 0) out[0] = 0.0f;

    const int row  = b * 4 + (threadIdx.x >> 6);
    const int lane = threadIdx.x & 63;

    const float4 qv = ((const float4*)(q + (size_t)row * D_DIM))[lane];
    const float4 dv = ((const float4*)(d + (size_t)row * D_DIM))[lane];

    float qss = qv.x*qv.x + qv.y*qv.y + qv.z*qv.z + qv.w*qv.w;
    float dss = dv.x*dv.x + dv.y*dv.y + dv.z*dv.z + dv.w*dv.w;
    float qd  = qv.x*dv.x + qv.y*dv.y + qv.z*dv.z + qv.w*dv.w;
#pragma unroll
    for (int off = 32; off; off >>= 1) {
        qss += __shfl_down(qss, off);
        dss += __shfl_down(dss, off);
        qd  += __shfl_down(qd,  off);
    }
    qss = __shfl(qss, 0);
    dss = __shfl(dss, 0);
    qd  = __shfl(qd,  0);

    const float qinv = 1.0f / fmaxf(sqrtf(qss), 1e-12f);
    const float dinv = 1.0f / fmaxf(sqrtf(dss), 1e-12f);

    struct alignas(8) bf4 { __hip_bfloat16 x, y, z, w; };
    bf4 qo, doo;
    qo.x = __float2bfloat16(qv.x * qinv);
    qo.y = __float2bfloat16(qv.y * qinv);
    qo.z = __float2bfloat16(qv.z * qinv);
    qo.w = __float2bfloat16(qv.w * qinv);
    doo.x = __float2bfloat16(dv.x * dinv);
    doo.y = __float2bfloat16(dv.y * dinv);
    doo.z = __float2bfloat16(dv.z * dinv);
    doo.w = __float2bfloat16(dv.w * dinv);
    *(bf4*)(qn + (size_t)row * D_DIM + lane * 4) = qo;
    *(bf4*)(dn + (size_t)row * D_DIM + lane * 4) = doo;

    if (lane == 0) diag[row] = qd * qinv * dinv * TEMP_INV;
}

// Kernel 2: 128x128 tile of sim = qn . dn^T; fused exp(sim - 1/T) row/col partial sums.
// R2 core (measured best: 234 us, 0 bank conflicts): BK=64, XOR-swizzled LDS.
// Physical 16B-chunk p of row r holds logical chunk p^(r&7); staging keeps the
// wave-uniform-base + lane*16 contiguity global_load_lds requires.
// Epilogue: butterfly ALL-TO-ALL reduce (15+3 shuffles vs 72) -> each lane holds one
// complete row/col partial sum -> one direct global atomicAdd per lane. No LDS bufs.
__global__ __launch_bounds__(256) void gemm_lse_kernel(
    const __hip_bfloat16* __restrict__ qn, const __hip_bfloat16* __restrict__ dn,
    float* __restrict__ row_sums, float* __restrict__ col_sums) {
    __shared__ __hip_bfloat16 As[BM][BK];   // 16 KB
    __shared__ __hip_bfloat16 Bs[BN][BK];   // 16 KB

    const int t    = threadIdx.x;
    const int lane = t & 63;
    const int w    = t >> 6;
    const int l15  = lane & 15;
    const int quad = lane >> 4;
    const int m0   = (w >> 1) * 64;
    const int n0   = (w & 1) * 64;
    const int rowBase = blockIdx.y * BM;
    const int colBase = blockIdx.x * BN;

    // staging map: thread t -> row t/8, GLOBAL k-chunk ((t&7)^(row&7)); LDS offset = t*16B
    const int rsub = t >> 3;
    const int ksub = (((t & 7) ^ (rsub & 7)) << 3);
    const __hip_bfloat16* ga = qn + (size_t)(rowBase + rsub) * D_DIM + ksub;
    const __hip_bfloat16* gb = dn + (size_t)(colBase + rsub) * D_DIM + ksub;
    __hip_bfloat16* la = &As[0][0] + t * 8;   // physical slot, unswizzled
    __hip_bfloat16* lb = &Bs[0][0] + t * 8;

    frag_cd acc[4][4];
#pragma unroll
    for (int i = 0; i < 4; ++i)
#pragma unroll
        for (int j = 0; j < 4; ++j)
            acc[i][j] = (frag_cd){0.0f, 0.0f, 0.0f, 0.0f};

    for (int kt = 0; kt < D_DIM; kt += BK) {
        if (kt) __syncthreads();
#pragma unroll
        for (int it = 0; it < 4; ++it) {   // +32 rows: (row&7) invariant, same swizzle
            gld_lds16(ga + (size_t)it * 32 * D_DIM + kt, la + it * 32 * BK);
            gld_lds16(gb + (size_t)it * 32 * D_DIM + kt, lb + it * 32 * BK);
        }
        __syncthreads();   // drains vmcnt (global_load_lds) + orders LDS

#pragma unroll
        for (int kk = 0; kk < BK; kk += 32) {
            const int c = (kk >> 3) + quad;          // logical 16B-chunk index
            frag_ab af[4], bfr[4];
#pragma unroll
            for (int i = 0; i < 4; ++i) {
                const int R = m0 + i * 16 + l15;
                af[i]  = *(const frag_ab*)&As[R][(c ^ (l15 & 7)) << 3];
            }
#pragma unroll
            for (int i = 0; i < 4; ++i) {
                const int R = n0 + i * 16 + l15;
                bfr[i] = *(const frag_ab*)&Bs[R][(c ^ (l15 & 7)) << 3];
            }
#pragma unroll
            for (int mi = 0; mi < 4; ++mi)
#pragma unroll
                for (int ni = 0; ni < 4; ++ni)
                    acc[mi][ni] = __builtin_amdgcn_mfma_f32_16x16x32_bf16(
                        af[mi], bfr[ni], acc[mi][ni], 0, 0, 0);
        }
    }

    // ---- Epilogue ----
    // C frag layout (m89): lane holds col = n0+ni*16+l15, row = m0+mi*16+quad*4+r.
    // rv[p], p = mi*4+r : row partials (summed over this lane's 4 ni-cols)
    // cv[ni]            : col partials (summed over this lane's 16 mi/r-rows)
    float rv[16];
    float cv[4] = {0.0f, 0.0f, 0.0f, 0.0f};
#pragma unroll
    for (int p = 0; p < 16; ++p) rv[p] = 0.0f;
#pragma unroll
    for (int mi = 0; mi < 4; ++mi)
#pragma unroll
        for (int ni = 0; ni < 4; ++ni)
#pragma unroll
            for (int r = 0; r < 4; ++r) {
                const float e = __expf((acc[mi][ni][r] - 1.0f) * TEMP_INV);
                rv[mi * 4 + r] += e;
                cv[ni] += e;
            }

    // Row butterfly all-reduce over the 16 lanes of each quad (lane bits 0..3).
    // After step s, rv[i] holds p = (i<<(s+1)) | (l15 & ((2<<s)-1)); end: rv[0] <-> p = l15.
#pragma unroll
    for (int s = 0; s < 4; ++s) {
        const bool b = (l15 >> s) & 1;
#pragma unroll
        for (int i = 0; i < (8 >> s); ++i) {
            const float a0 = rv[2 * i], a1 = rv[2 * i + 1];
            const float keep = b ? a1 : a0;
            const float send = b ? a0 : a1;
            rv[i] = keep + __shfl_xor(send, 1 << s);
        }
    }
    atomicAdd(&row_sums[rowBase + m0 + (l15 >> 2) * 16 + quad * 4 + (l15 & 3)], rv[0]);

    // Col butterfly all-reduce over the 4 quads (lane bits 4..5); end: cv[0] <-> ni = quad.
#pragma unroll
    for (int s = 0; s < 2; ++s) {
        const bool b = (quad >> s) & 1;
#pragma unroll
        for (int i = 0; i < (2 >> s); ++i) {
            const float a0 = cv[2 * i], a1 = cv[2 * i + 1];
            const float keep = b ? a1 : a0;
            const float send = b ? a0 : a1;
            cv[i] = keep + __shfl_xor(send, 16 << s);
        }
    }
    atomicAdd(&col_sums[colBase + n0 + quad * 16 + l15], cv[0]);
}

// Kernel 3 (parallel): each block reduces 256 rows, atomicAdd into zeroed out[0].
__global__ __launch_bounds__(256) void finalize_kernel(
    const float* __restrict__ rs, const float* __restrict__ cs,
    const float* __restrict__ dg, float* __restrict__ out) {
    const int i = blockIdx.x * 256 + threadIdx.x;
    float s = logf(rs[i]) + logf(cs[i]) - 2.0f * dg[i];
#pragma unroll
    for (int off = 32; off; off >>= 1) s += __shfl_down(s, off);
    __shared__ float buf[4];
    if ((threadIdx.x & 63) == 0) buf[threadIdx.x >> 6] = s;
    __syncthreads();
    if (threadIdx.x == 0) {
        float tot = (buf[0] + buf[1] + buf[2] + buf[3]) / (2.0f * B_ROWS);
        if (blockIdx.x == 0) tot += TEMP_INV;   // undo the fixed exp shift
        atomicAdd(out, tot);
    }
}

extern "C" void kernel_launch(void* const* d_in, const int* in_sizes, int n_in,
                              void* d_out, int out_size, void* d_ws, size_t ws_size,
                              hipStream_t stream) {
    const float* q = (const float*)d_in[0];
    const float* d = (const float*)d_in[1];
    float* out = (float*)d_out;

    char* ws = (char*)d_ws;
    __hip_bfloat16* qn = (__hip_bfloat16*)ws;                       // 8 MB
    __hip_bfloat16* dn = qn + (size_t)B_ROWS * D_DIM;               // 8 MB
    float* row_sums = (float*)(ws + 2 * (size_t)B_ROWS * D_DIM * sizeof(__hip_bfloat16));
    float* col_sums = row_sums + B_ROWS;
    float* diag     = col_sums + B_ROWS;

    norm_diag_kernel<<<B_ROWS / 4, 256, 0, stream>>>(q, d, qn, dn, diag,
                                                     row_sums, col_sums, out);
    gemm_lse_kernel<<<dim3(B_ROWS / BN, B_ROWS / BM), 256, 0, stream>>>(qn, dn, row_sums, col_sums);
    finalize_kernel<<<B_ROWS / 256, 256, 0, stream>>>(row_sums, col_sums, diag, out);
}